// Round 6
// baseline (2200.954 us; speedup 1.0000x reference)
//
#include <hip/hip_runtime.h>

#define B_ 4
#define S_ 16384
#define E_ 16
#define T_ 4096
#define N_ 8192

// ---------------------------------------------------------------------------
// P1: top-8 nearest sources per grid point. One thread per t, sequential scan.
// Strict < insert keeps earliest index on ties == jax.lax.top_k ordering.
// ---------------------------------------------------------------------------
__global__ void p1_topk(const float* cs, const float* cg, int* oidx) {
  int t = blockIdx.x * 64 + threadIdx.x;
  if (t >= T_) return;
  float gx = cg[t], gy = cg[T_ + t];
  float dd[8]; int ii[8];
#pragma unroll
  for (int k = 0; k < 8; ++k) { dd[k] = 3.0e38f; ii[k] = 0; }
  for (int s = 0; s < S_; ++s) {
    float dx = gx - cs[s];
    float dy = gy - cs[S_ + s];
    float d2 = __fadd_rn(__fmul_rn(dx, dx), __fmul_rn(dy, dy));
    float cd = d2; int ci = s;
#pragma unroll
    for (int j = 0; j < 8; ++j) {
      bool sw = cd < dd[j];
      float td = dd[j]; int ti = ii[j];
      dd[j] = sw ? cd : td; ii[j] = sw ? ci : ti;
      cd = sw ? td : cd;    ci = sw ? ti : ci;
    }
  }
#pragma unroll
  for (int k = 0; k < 8; ++k) oidx[t * 8 + k] = ii[k];
}

// ---------------------------------------------------------------------------
// P2: per grid point t: all 8 neighbors' MLP+LayerNorm, logits, softmax.
// One thread per t, fully sequential, scalar loads only.
// ---------------------------------------------------------------------------
__global__ void p2_weights(const float* cs, const float* cg, const int* idx,
                           const float* pw1, const float* pb1,
                           const float* pw2, const float* pb2,
                           const float* lng, const float* lnb,
                           const float* kw, const float* kb,
                           float* outw) {
  int t = blockIdx.x * 64 + threadIdx.x;
  if (t >= T_) return;
  float lg[8];
#pragma unroll
  for (int h = 0; h < 8; ++h) lg[h] = kb[h];
  for (int n = 0; n < 8; ++n) {
    int s = idx[t * 8 + n];
    float r0 = cs[s] - cg[t];
    float r1 = cs[S_ + s] - cg[T_ + t];
    float pe[32];
#pragma unroll
    for (int d = 0; d < 32; ++d) pe[d] = pb2[d];
    for (int f = 0; f < 64; ++f) {
      float a = fmaf(r0, pw1[f], fmaf(r1, pw1[64 + f], pb1[f]));
      // jax.nn.gelu approximate=True
      float u = 0.7978845608028654f * (a + 0.044715f * a * a * a);
      float g = 0.5f * a * (1.0f + tanhf(u));
#pragma unroll
      for (int d = 0; d < 32; ++d) pe[d] = fmaf(g, pw2[f * 32 + d], pe[d]);
    }
    float mu = 0.f;
#pragma unroll
    for (int d = 0; d < 32; ++d) mu += pe[d];
    mu *= (1.0f / 32.0f);
    float var = 0.f;
#pragma unroll
    for (int d = 0; d < 32; ++d) { float df = pe[d] - mu; var = fmaf(df, df, var); }
    var *= (1.0f / 32.0f);
    float rs = rsqrtf(var + 1e-5f);
#pragma unroll
    for (int d = 0; d < 32; ++d) {
      float kf = fmaf((pe[d] - mu) * rs, lng[d], lnb[d]);
#pragma unroll
      for (int h = 0; h < 8; ++h)
        lg[h] = fmaf(kf, kw[(n * 32 + d) * 8 + h], lg[h]);
    }
  }
  float m = lg[0];
#pragma unroll
  for (int h = 1; h < 8; ++h) m = fmaxf(m, lg[h]);
  float es[8]; float ssum = 0.f;
#pragma unroll
  for (int h = 0; h < 8; ++h) { es[h] = expf(lg[h] - m); ssum += es[h]; }
#pragma unroll
  for (int h = 0; h < 8; ++h) outw[t * 8 + h] = es[h] / ssum;
}

// ---------------------------------------------------------------------------
// P3: grid[b,t,e] = sum_n x[b, idx[t,n], e] * w[t,n]   (layout B,T,E)
// ---------------------------------------------------------------------------
__global__ void p3_grid(const float* x, const int* idx, const float* w,
                        float* grid) {
  int tid = blockIdx.x * 256 + threadIdx.x;
  int e = tid & 15;
  int t = (tid >> 4) & (T_ - 1);
  int b = tid >> 16;
  float acc = 0.f;
  for (int nn = 0; nn < 8; ++nn) {
    int s = idx[t * 8 + nn];
    acc = fmaf(x[(b * S_ + s) * 16 + e], w[t * 8 + nn], acc);
  }
  grid[tid] = acc;
}

// ---------------------------------------------------------------------------
// P45: per (b,n,e): Gaussian tap weights (recomputed per channel; separable
// normalization == reference's joint normalization) + 25-tap gather.
// ---------------------------------------------------------------------------
__global__ void p45(const float* ct, const float* grid, float* out) {
  int tid = blockIdx.x * 256 + threadIdx.x;   // (b*N + n)*16 + e
  int e = tid & 15;
  int bn = tid >> 4;
  int b = bn >> 13;                            // N = 8192
  float cy = ct[bn * 2 + 0];
  float cx = ct[bn * 2 + 1];
  float posx = cx * 63.0f, posy = cy * 63.0f;
  float rpx = rintf(posx), rpy = rintf(posy);  // rint = round-half-even = jnp.round
  float wx[5], wy[5];
  float sx = 0.f, sy = 0.f;
#pragma unroll
  for (int p = 0; p < 5; ++p) {
    float ax = 0.f, ay = 0.f;
    for (int jj = 0; jj < 18; ++jj) {
      int j = p * 18 + jj;
      float off = 2.5f - (5.0f * (float)j) / 89.0f;
      float px = fminf(fmaxf(rpx - off, 0.0f), 64.0f);
      float py = fminf(fmaxf(rpy - off, 0.0f), 64.0f);
      float dx = px - posx, dy = py - posy;
      ax += expf(-2.0f * dx * dx);   // 1/(sig*sqrt(2pi)) cancels in normalization
      ay += expf(-2.0f * dy * dy);
    }
    wx[p] = ax; sx += ax;
    wy[p] = ay; sy += ay;
  }
  float isx = 1.0f / sx, isy = 1.0f / sy;
  int irpx = (int)rpx, irpy = (int)rpy;
  const float* gb = grid + (b << 16);          // b*T*E
  float acc = 0.f;
#pragma unroll
  for (int p = 0; p < 5; ++p) {
    int vx = irpx - (p - 2); vx = vx < 0 ? 0 : (vx > 63 ? 63 : vx);
    float wxp = wx[p] * isx;
#pragma unroll
    for (int q = 0; q < 5; ++q) {
      int vy = irpy - (q - 2); vy = vy < 0 ? 0 : (vy > 63 ? 63 : vy);
      acc = fmaf(wxp * (wy[q] * isy), gb[(vx << 10) + (vy << 4) + e], acc);
    }
  }
  out[tid] = acc;
}

// ---------------------------------------------------------------------------
extern "C" void kernel_launch(void* const* d_in, const int* in_sizes, int n_in,
                              void* d_out, int out_size, void* d_ws, size_t ws_size,
                              hipStream_t stream) {
  const float* x   = (const float*)d_in[0];
  const float* cs  = (const float*)d_in[1];
  const float* cg  = (const float*)d_in[2];
  const float* ct  = (const float*)d_in[3];
  const float* pw1 = (const float*)d_in[4];
  const float* pb1 = (const float*)d_in[5];
  const float* pw2 = (const float*)d_in[6];
  const float* pb2 = (const float*)d_in[7];
  const float* lng = (const float*)d_in[8];
  const float* lnb = (const float*)d_in[9];
  const float* kw  = (const float*)d_in[10];
  const float* kb  = (const float*)d_in[11];
  float* out = (float*)d_out;
  char* ws = (char*)d_ws;

  int*   w_idx  = (int*)  (ws + 0);         // T*8*4   = 131072
  float* w_w    = (float*)(ws + 131072);    // T*8*4   = 131072
  float* w_grid = (float*)(ws + 262144);    // B*T*E*4 = 1048576  (total 1.25 MB)

  p1_topk<<<dim3(T_ / 64), dim3(64), 0, stream>>>(cs, cg, w_idx);
  p2_weights<<<dim3(T_ / 64), dim3(64), 0, stream>>>(
      cs, cg, w_idx, pw1, pb1, pw2, pb2, lng, lnb, kw, kb, w_w);
  p3_grid<<<dim3(B_ * T_ * E_ / 256), dim3(256), 0, stream>>>(x, w_idx, w_w, w_grid);
  p45<<<dim3(B_ * N_ * E_ / 256), dim3(256), 0, stream>>>(ct, w_grid, out);
}